// Round 1
// baseline (1727.588 us; speedup 1.0000x reference)
//
#include <hip/hip_runtime.h>
#include <math.h>

#define NB 8
#define TS 2048
#define DM 384
#define NH 6
#define HD 64
#define E3 1152
#define MROWS (NB*TS)

// ---------------- RoPE cos/sin table: [T, 64] ----------------
__global__ void rope_table_k(float* __restrict__ cosT, float* __restrict__ sinT) {
    int i = blockIdx.x * 256 + threadIdx.x;
    if (i >= TS * HD) return;
    int t   = i >> 6;
    int idx = i & 63;
    int fi  = idx & 31;                       // emb = concat(freqs, freqs)
    float inv = expf(-(float)fi * (logf(10000.0f) * (1.0f / 32.0f)));
    float ang = (float)t * inv;
    cosT[i] = cosf(ang);
    sinT[i] = sinf(ang);
}

// ---------------- QKV GEMM: qkv[r,e] = sum_d x[r,d]*Wqkv[e,d] ----------------
// 64x64 tile, BK=32, 256 thr, 4x4/thread. Epilogue scatters into [N,H,T,hd].
__global__ __launch_bounds__(256) void qkv_gemm_k(
    const float* __restrict__ X, const float* __restrict__ W,
    float* __restrict__ qb, float* __restrict__ kb, float* __restrict__ vb) {
    __shared__ float As[32 * 68];   // [k][m], stride 68 to dodge bank conflicts
    __shared__ float Bs[32 * 68];   // [k][e]
    int tid  = threadIdx.x;
    int row0 = blockIdx.x * 64;
    int col0 = blockIdx.y * 64;
    int tr = (tid >> 4) << 2;
    int tc = (tid & 15) << 2;
    float acc[4][4] = {};

    for (int kt = 0; kt < DM; kt += 32) {
        __syncthreads();
        #pragma unroll
        for (int j = 0; j < 2; ++j) {
            int li = tid + j * 256;          // 0..511
            int m  = li >> 3;                // 0..63
            int k4 = (li & 7) << 2;          // 0..28
            float4 av = *(const float4*)&X[(size_t)(row0 + m) * DM + kt + k4];
            As[(k4+0)*68 + m] = av.x; As[(k4+1)*68 + m] = av.y;
            As[(k4+2)*68 + m] = av.z; As[(k4+3)*68 + m] = av.w;
            float4 bv = *(const float4*)&W[(size_t)(col0 + m) * DM + kt + k4];
            Bs[(k4+0)*68 + m] = bv.x; Bs[(k4+1)*68 + m] = bv.y;
            Bs[(k4+2)*68 + m] = bv.z; Bs[(k4+3)*68 + m] = bv.w;
        }
        __syncthreads();
        #pragma unroll
        for (int k = 0; k < 32; ++k) {
            float4 a = *(float4*)&As[k*68 + tr];
            float4 b = *(float4*)&Bs[k*68 + tc];
            acc[0][0] = fmaf(a.x, b.x, acc[0][0]); acc[0][1] = fmaf(a.x, b.y, acc[0][1]);
            acc[0][2] = fmaf(a.x, b.z, acc[0][2]); acc[0][3] = fmaf(a.x, b.w, acc[0][3]);
            acc[1][0] = fmaf(a.y, b.x, acc[1][0]); acc[1][1] = fmaf(a.y, b.y, acc[1][1]);
            acc[1][2] = fmaf(a.y, b.z, acc[1][2]); acc[1][3] = fmaf(a.y, b.w, acc[1][3]);
            acc[2][0] = fmaf(a.z, b.x, acc[2][0]); acc[2][1] = fmaf(a.z, b.y, acc[2][1]);
            acc[2][2] = fmaf(a.z, b.z, acc[2][2]); acc[2][3] = fmaf(a.z, b.w, acc[2][3]);
            acc[3][0] = fmaf(a.w, b.x, acc[3][0]); acc[3][1] = fmaf(a.w, b.y, acc[3][1]);
            acc[3][2] = fmaf(a.w, b.z, acc[3][2]); acc[3][3] = fmaf(a.w, b.w, acc[3][3]);
        }
    }
    // Epilogue: whole 64-col tile lies in exactly one of {q,k,v} and one head.
    int which = col0 / DM;
    int h     = (col0 % DM) >> 6;
    int n     = row0 / TS;                   // 64 | 2048, uniform per block
    float* dst = (which == 0) ? qb : (which == 1) ? kb : vb;
    #pragma unroll
    for (int i = 0; i < 4; ++i) {
        int r = row0 + tr + i;
        int t = r & (TS - 1);
        float4 ov = make_float4(acc[i][0], acc[i][1], acc[i][2], acc[i][3]);
        *(float4*)&dst[(((size_t)n * NH + h) * TS + t) * HD + tc] = ov;
    }
}

// ---------------- in-place RoPE on q and k ----------------
__global__ void rope_apply_k(float* __restrict__ qb, float* __restrict__ kb,
                             const float* __restrict__ cosT, const float* __restrict__ sinT) {
    const int NPAIR = NB * NH * TS * 32;
    int gid = blockIdx.x * 256 + threadIdx.x;
    float* buf = (gid < NPAIR) ? qb : kb;
    int g   = (gid < NPAIR) ? gid : gid - NPAIR;
    int p   = g & 31;
    int row = g >> 5;                  // [0, NB*NH*TS)
    int t   = row & (TS - 1);
    size_t base = (size_t)row * HD;
    float c = cosT[t * HD + p];
    float s = sinT[t * HD + p];
    float a = buf[base + p];
    float b = buf[base + p + 32];
    buf[base + p]      = a * c - b * s;
    buf[base + p + 32] = b * c + a * s;
}

// ---------------- causal flash attention, fp32 ----------------
// 1 q-row per thread, 256 rows/block, K/V staged 64 rows at a time in LDS.
__global__ __launch_bounds__(256) void flash_k(
    const float* __restrict__ qb, const float* __restrict__ kb,
    const float* __restrict__ vb, float* __restrict__ ctx) {
    __shared__ float Ks[64 * 64];
    __shared__ float Vs[64 * 64];
    int tid = threadIdx.x;
    int nh  = blockIdx.y;              // n*NH + h
    int qt  = blockIdx.x;
    int qidx = qt * 256 + tid;

    const float* qrow = qb + ((size_t)nh * TS + qidx) * HD;
    float4 qv[16], o[16];
    #pragma unroll
    for (int j = 0; j < 16; ++j) { qv[j] = *(const float4*)&qrow[j * 4]; o[j] = make_float4(0,0,0,0); }
    float mM = -INFINITY, l = 0.0f;
    const float scale = 0.125f;        // 1/sqrt(64)

    int nkt = qt * 4 + 4;              // k-tiles up to causal boundary of block
    for (int kt2 = 0; kt2 < nkt; ++kt2) {
        __syncthreads();
        #pragma unroll
        for (int i = 0; i < 4; ++i) {
            int li = tid + i * 256;
            int r  = li >> 4;
            int c  = (li & 15) << 2;
            size_t src = ((size_t)nh * TS + kt2 * 64 + r) * HD + c;
            *(float4*)&Ks[r * 64 + c] = *(const float4*)&kb[src];
            *(float4*)&Vs[r * 64 + c] = *(const float4*)&vb[src];
        }
        __syncthreads();
        int kmax_local = qidx - kt2 * 64;     // valid kk <= this
        for (int kk = 0; kk < 64; ++kk) {
            if (kk > kmax_local) break;       // causal: rest of tile invalid too
            const float4* kr = (const float4*)&Ks[kk * 64];   // broadcast reads
            float sa = 0, sb = 0, sc = 0, sd = 0;
            #pragma unroll
            for (int j = 0; j < 16; ++j) {
                float4 kv4 = kr[j];
                sa = fmaf(qv[j].x, kv4.x, sa);
                sb = fmaf(qv[j].y, kv4.y, sb);
                sc = fmaf(qv[j].z, kv4.z, sc);
                sd = fmaf(qv[j].w, kv4.w, sd);
            }
            float s = ((sa + sb) + (sc + sd)) * scale;
            if (s > mM) {                      // rare after warmup (~ln(T) times)
                float corr = __expf(mM - s);   // mM=-inf -> corr=0, correct init
                mM = s;
                l *= corr;
                #pragma unroll
                for (int j = 0; j < 16; ++j) {
                    o[j].x *= corr; o[j].y *= corr; o[j].z *= corr; o[j].w *= corr;
                }
            }
            float p = __expf(s - mM);
            l += p;
            const float4* vr = (const float4*)&Vs[kk * 64];
            #pragma unroll
            for (int j = 0; j < 16; ++j) {
                float4 vv = vr[j];
                o[j].x = fmaf(p, vv.x, o[j].x);
                o[j].y = fmaf(p, vv.y, o[j].y);
                o[j].z = fmaf(p, vv.z, o[j].z);
                o[j].w = fmaf(p, vv.w, o[j].w);
            }
        }
    }
    float invl = 1.0f / l;                     // every row has >=1 valid key
    int n = nh / NH, h = nh % NH;
    float* crow = ctx + ((size_t)(n * TS + qidx)) * DM + h * HD;
    #pragma unroll
    for (int j = 0; j < 16; ++j) {
        float4 ov = o[j];
        ov.x *= invl; ov.y *= invl; ov.z *= invl; ov.w *= invl;
        *(float4*)&crow[j * 4] = ov;
    }
}

// ---------------- out projection: out[r,e] = sum_d ctx[r,d]*Wout[e,d] ----------------
__global__ __launch_bounds__(256) void outproj_gemm_k(
    const float* __restrict__ X, const float* __restrict__ W, float* __restrict__ out) {
    __shared__ float As[32 * 68];
    __shared__ float Bs[32 * 68];
    int tid  = threadIdx.x;
    int row0 = blockIdx.x * 64;
    int col0 = blockIdx.y * 64;
    int tr = (tid >> 4) << 2;
    int tc = (tid & 15) << 2;
    float acc[4][4] = {};

    for (int kt = 0; kt < DM; kt += 32) {
        __syncthreads();
        #pragma unroll
        for (int j = 0; j < 2; ++j) {
            int li = tid + j * 256;
            int m  = li >> 3;
            int k4 = (li & 7) << 2;
            float4 av = *(const float4*)&X[(size_t)(row0 + m) * DM + kt + k4];
            As[(k4+0)*68 + m] = av.x; As[(k4+1)*68 + m] = av.y;
            As[(k4+2)*68 + m] = av.z; As[(k4+3)*68 + m] = av.w;
            float4 bv = *(const float4*)&W[(size_t)(col0 + m) * DM + kt + k4];
            Bs[(k4+0)*68 + m] = bv.x; Bs[(k4+1)*68 + m] = bv.y;
            Bs[(k4+2)*68 + m] = bv.z; Bs[(k4+3)*68 + m] = bv.w;
        }
        __syncthreads();
        #pragma unroll
        for (int k = 0; k < 32; ++k) {
            float4 a = *(float4*)&As[k*68 + tr];
            float4 b = *(float4*)&Bs[k*68 + tc];
            acc[0][0] = fmaf(a.x, b.x, acc[0][0]); acc[0][1] = fmaf(a.x, b.y, acc[0][1]);
            acc[0][2] = fmaf(a.x, b.z, acc[0][2]); acc[0][3] = fmaf(a.x, b.w, acc[0][3]);
            acc[1][0] = fmaf(a.y, b.x, acc[1][0]); acc[1][1] = fmaf(a.y, b.y, acc[1][1]);
            acc[1][2] = fmaf(a.y, b.z, acc[1][2]); acc[1][3] = fmaf(a.y, b.w, acc[1][3]);
            acc[2][0] = fmaf(a.z, b.x, acc[2][0]); acc[2][1] = fmaf(a.z, b.y, acc[2][1]);
            acc[2][2] = fmaf(a.z, b.z, acc[2][2]); acc[2][3] = fmaf(a.z, b.w, acc[2][3]);
            acc[3][0] = fmaf(a.w, b.x, acc[3][0]); acc[3][1] = fmaf(a.w, b.y, acc[3][1]);
            acc[3][2] = fmaf(a.w, b.z, acc[3][2]); acc[3][3] = fmaf(a.w, b.w, acc[3][3]);
        }
    }
    #pragma unroll
    for (int i = 0; i < 4; ++i) {
        int r = row0 + tr + i;
        float4 ov = make_float4(acc[i][0], acc[i][1], acc[i][2], acc[i][3]);
        *(float4*)&out[(size_t)r * DM + col0 + tc] = ov;
    }
}

extern "C" void kernel_launch(void* const* d_in, const int* in_sizes, int n_in,
                              void* d_out, int out_size, void* d_ws, size_t ws_size,
                              hipStream_t stream) {
    const float* x    = (const float*)d_in[0];
    const float* Wqkv = (const float*)d_in[1];
    const float* Wout = (const float*)d_in[2];
    float* out = (float*)d_out;

    float* ws   = (float*)d_ws;
    const size_t NHT = (size_t)NB * NH * TS * HD;   // 6.29M floats per tensor
    float* cosT = ws;
    float* sinT = cosT + TS * HD;
    float* qb   = sinT + TS * HD;
    float* kb   = qb + NHT;
    float* vb   = kb + NHT;
    float* ctx  = vb + NHT;                         // [N,T,D]
    // total ws: ~25.4M floats (~102 MB)

    rope_table_k<<<(TS * HD) / 256, 256, 0, stream>>>(cosT, sinT);
    qkv_gemm_k<<<dim3(MROWS / 64, E3 / 64), 256, 0, stream>>>(x, Wqkv, qb, kb, vb);
    rope_apply_k<<<(2 * NB * NH * TS * 32) / 256, 256, 0, stream>>>(qb, kb, cosT, sinT);
    flash_k<<<dim3(TS / 256, NB * NH), 256, 0, stream>>>(qb, kb, vb, ctx);
    outproj_gemm_k<<<dim3(MROWS / 64, DM / 64), 256, 0, stream>>>(ctx, Wout, out);
}

// Round 2
// 689.403 us; speedup vs baseline: 2.5059x; 2.5059x over previous
//
#include <hip/hip_runtime.h>
#include <math.h>

#define NB 8
#define TS 2048
#define DM 384
#define NH 6
#define HD 64
#define E3 1152
#define MROWS (NB*TS)

typedef __attribute__((ext_vector_type(8))) short bf16x8;
typedef __attribute__((ext_vector_type(4))) float f32x4;

__device__ __forceinline__ ushort f2bf(float f) {
    uint u = __float_as_uint(f);
    uint r = (u + 0x7FFFu + ((u >> 16) & 1u)) >> 16;
    return (ushort)r;
}
__device__ __forceinline__ float bf2f(ushort h) {
    return __uint_as_float(((uint)h) << 16);
}

// ---------------- RoPE cos/sin table: [T, 64] ----------------
__global__ void rope_table_k(float* __restrict__ cosT, float* __restrict__ sinT) {
    int i = blockIdx.x * 256 + threadIdx.x;
    if (i >= TS * HD) return;
    int t   = i >> 6;
    int idx = i & 63;
    int fi  = idx & 31;
    float inv = expf(-(float)fi * (logf(10000.0f) * (1.0f / 32.0f)));
    float ang = (float)t * inv;
    cosT[i] = cosf(ang);
    sinT[i] = sinf(ang);
}

// ---------------- QKV GEMM (fp32 VALU, unchanged) ----------------
__global__ __launch_bounds__(256) void qkv_gemm_k(
    const float* __restrict__ X, const float* __restrict__ W,
    float* __restrict__ qb, float* __restrict__ kb, float* __restrict__ vb) {
    __shared__ float As[32 * 68];
    __shared__ float Bs[32 * 68];
    int tid  = threadIdx.x;
    int row0 = blockIdx.x * 64;
    int col0 = blockIdx.y * 64;
    int tr = (tid >> 4) << 2;
    int tc = (tid & 15) << 2;
    float acc[4][4] = {};

    for (int kt = 0; kt < DM; kt += 32) {
        __syncthreads();
        #pragma unroll
        for (int j = 0; j < 2; ++j) {
            int li = tid + j * 256;
            int m  = li >> 3;
            int k4 = (li & 7) << 2;
            float4 av = *(const float4*)&X[(size_t)(row0 + m) * DM + kt + k4];
            As[(k4+0)*68 + m] = av.x; As[(k4+1)*68 + m] = av.y;
            As[(k4+2)*68 + m] = av.z; As[(k4+3)*68 + m] = av.w;
            float4 bv = *(const float4*)&W[(size_t)(col0 + m) * DM + kt + k4];
            Bs[(k4+0)*68 + m] = bv.x; Bs[(k4+1)*68 + m] = bv.y;
            Bs[(k4+2)*68 + m] = bv.z; Bs[(k4+3)*68 + m] = bv.w;
        }
        __syncthreads();
        #pragma unroll
        for (int k = 0; k < 32; ++k) {
            float4 a = *(float4*)&As[k*68 + tr];
            float4 b = *(float4*)&Bs[k*68 + tc];
            acc[0][0] = fmaf(a.x, b.x, acc[0][0]); acc[0][1] = fmaf(a.x, b.y, acc[0][1]);
            acc[0][2] = fmaf(a.x, b.z, acc[0][2]); acc[0][3] = fmaf(a.x, b.w, acc[0][3]);
            acc[1][0] = fmaf(a.y, b.x, acc[1][0]); acc[1][1] = fmaf(a.y, b.y, acc[1][1]);
            acc[1][2] = fmaf(a.y, b.z, acc[1][2]); acc[1][3] = fmaf(a.y, b.w, acc[1][3]);
            acc[2][0] = fmaf(a.z, b.x, acc[2][0]); acc[2][1] = fmaf(a.z, b.y, acc[2][1]);
            acc[2][2] = fmaf(a.z, b.z, acc[2][2]); acc[2][3] = fmaf(a.z, b.w, acc[2][3]);
            acc[3][0] = fmaf(a.w, b.x, acc[3][0]); acc[3][1] = fmaf(a.w, b.y, acc[3][1]);
            acc[3][2] = fmaf(a.w, b.z, acc[3][2]); acc[3][3] = fmaf(a.w, b.w, acc[3][3]);
        }
    }
    int which = col0 / DM;
    int h     = (col0 % DM) >> 6;
    int n     = row0 / TS;
    float* dst = (which == 0) ? qb : (which == 1) ? kb : vb;
    #pragma unroll
    for (int i = 0; i < 4; ++i) {
        int r = row0 + tr + i;
        int t = r & (TS - 1);
        float4 ov = make_float4(acc[i][0], acc[i][1], acc[i][2], acc[i][3]);
        *(float4*)&dst[(((size_t)n * NH + h) * TS + t) * HD + tc] = ov;
    }
}

// ---------------- in-place RoPE on q and k ----------------
__global__ void rope_apply_k(float* __restrict__ qb, float* __restrict__ kb,
                             const float* __restrict__ cosT, const float* __restrict__ sinT) {
    const int NPAIR = NB * NH * TS * 32;
    int gid = blockIdx.x * 256 + threadIdx.x;
    float* buf = (gid < NPAIR) ? qb : kb;
    int g   = (gid < NPAIR) ? gid : gid - NPAIR;
    int p   = g & 31;
    int row = g >> 5;
    int t   = row & (TS - 1);
    size_t base = (size_t)row * HD;
    float c = cosT[t * HD + p];
    float s = sinT[t * HD + p];
    float a = buf[base + p];
    float b = buf[base + p + 32];
    buf[base + p]      = a * c - b * s;
    buf[base + p + 32] = b * c + a * s;
}

// ---------------- MFMA flash attention ----------------
// Block: 256 thr = 4 waves; 128 q-rows (wave w: rows 32w..32w+31); 32-key tiles.
// Q,K hi/lo bf16 (3-term product => ~fp32 scores); V hi/lo; P bf16 (sum over
// quantized P keeps softmax a convex combination).
__global__ __launch_bounds__(256) void flash_mfma_k(
    const float* __restrict__ qb, const float* __restrict__ kb,
    const float* __restrict__ vb, float* __restrict__ ctx) {
    __shared__ ushort Khi[32 * 64];       // [key][d], XOR-swizzled
    __shared__ ushort Klo[32 * 64];
    __shared__ ushort Vhi[64 * 48];       // [d][key], stride 48 pad
    __shared__ ushort Vlo[64 * 48];
    __shared__ ushort Pl[4][32 * 48];     // per-wave P, [q][key], stride 48

    const int tid  = threadIdx.x;
    const int w    = tid >> 6;
    const int lane = tid & 63;
    const int g    = lane >> 4;           // 0..3
    const int c    = lane & 15;           // 0..15
    const int qt   = 15 - blockIdx.x;     // big tiles dispatched first
    const int nh   = blockIdx.y;
    const int qrow0 = qt * 128 + w * 32;
    const float scale = 0.125f;

    // ---- Q fragments (hi/lo), scale folded in ----
    bf16x8 qh[2][2], ql[2][2];            // [mf][kf]
    #pragma unroll
    for (int mf = 0; mf < 2; ++mf)
        #pragma unroll
        for (int kf = 0; kf < 2; ++kf) {
            const float* qs = qb + ((size_t)nh * TS + qrow0 + mf * 16 + c) * HD + kf * 32 + g * 8;
            float4 x0 = *(const float4*)qs;
            float4 x1 = *(const float4*)(qs + 4);
            float xv[8] = {x0.x, x0.y, x0.z, x0.w, x1.x, x1.y, x1.z, x1.w};
            bf16x8 hh, ll;
            #pragma unroll
            for (int j = 0; j < 8; ++j) {
                float xs = xv[j] * scale;
                ushort h = f2bf(xs);
                hh[j] = (short)h;
                ll[j] = (short)f2bf(xs - bf2f(h));
            }
            qh[mf][kf] = hh;
            ql[mf][kf] = ll;
        }

    f32x4 o[2][4];                        // [mf][nf_d]  D-layout rows 4g+r
    float mrun[2][4], lrun[2][4];
    #pragma unroll
    for (int mf = 0; mf < 2; ++mf) {
        #pragma unroll
        for (int nf = 0; nf < 4; ++nf) o[mf][nf] = (f32x4){0.f, 0.f, 0.f, 0.f};
        #pragma unroll
        for (int r = 0; r < 4; ++r) { mrun[mf][r] = -INFINITY; lrun[mf][r] = 0.f; }
    }

    const int nkt       = 4 * qt + 4;
    const int wave_last = 4 * qt + w;     // this wave's diagonal tile
    const int sk_key = tid >> 3, sk_d0 = (tid & 7) * 8;
    const int sv_key = tid & 31, sv_d0 = (tid >> 5) * 8;

    for (int kt = 0; kt < nkt; ++kt) {
        __syncthreads();
        {   // ---- stage K tile (hi/lo, swizzled) ----
            const float* src = kb + ((size_t)nh * TS + kt * 32 + sk_key) * HD + sk_d0;
            float4 a0 = *(const float4*)src;
            float4 a1 = *(const float4*)(src + 4);
            float xs[8] = {a0.x, a0.y, a0.z, a0.w, a1.x, a1.y, a1.z, a1.w};
            bf16x8 hv, lv;
            #pragma unroll
            for (int j = 0; j < 8; ++j) {
                ushort h = f2bf(xs[j]);
                hv[j] = (short)h;
                lv[j] = (short)f2bf(xs[j] - bf2f(h));
            }
            int dsw = sk_d0 ^ ((sk_key & 7) << 3);
            *(bf16x8*)&Khi[sk_key * 64 + dsw] = hv;
            *(bf16x8*)&Klo[sk_key * 64 + dsw] = lv;
            // ---- stage V tile transposed [d][key] ----
            const float* vs = vb + ((size_t)nh * TS + kt * 32 + sv_key) * HD + sv_d0;
            float4 v0 = *(const float4*)vs;
            float4 v1 = *(const float4*)(vs + 4);
            float vv[8] = {v0.x, v0.y, v0.z, v0.w, v1.x, v1.y, v1.z, v1.w};
            #pragma unroll
            for (int j = 0; j < 8; ++j) {
                ushort h = f2bf(vv[j]);
                Vhi[(sv_d0 + j) * 48 + sv_key] = h;
                Vlo[(sv_d0 + j) * 48 + sv_key] = f2bf(vv[j] - bf2f(h));
            }
        }
        __syncthreads();
        if (kt > wave_last) continue;

        // ---- K fragments ----
        bf16x8 kh[2][2], kl[2][2];        // [nf][kf]
        #pragma unroll
        for (int nf = 0; nf < 2; ++nf)
            #pragma unroll
            for (int kf = 0; kf < 2; ++kf) {
                int key = nf * 16 + c;
                int d   = (kf * 32 + g * 8) ^ ((key & 7) << 3);
                kh[nf][kf] = *(const bf16x8*)&Khi[key * 64 + d];
                kl[nf][kf] = *(const bf16x8*)&Klo[key * 64 + d];
            }

        // ---- S = Q K^T (3-term hi/lo) ----
        f32x4 s[2][2];
        #pragma unroll
        for (int mf = 0; mf < 2; ++mf)
            #pragma unroll
            for (int nf = 0; nf < 2; ++nf) {
                f32x4 acc = (f32x4){0.f, 0.f, 0.f, 0.f};
                #pragma unroll
                for (int kf = 0; kf < 2; ++kf) {
                    acc = __builtin_amdgcn_mfma_f32_16x16x32_bf16(qh[mf][kf], kh[nf][kf], acc, 0, 0, 0);
                    acc = __builtin_amdgcn_mfma_f32_16x16x32_bf16(ql[mf][kf], kh[nf][kf], acc, 0, 0, 0);
                    acc = __builtin_amdgcn_mfma_f32_16x16x32_bf16(qh[mf][kf], kl[nf][kf], acc, 0, 0, 0);
                }
                s[mf][nf] = acc;
            }

        // ---- causal mask on diagonal tile ----
        if (kt == wave_last) {
            #pragma unroll
            for (int mf = 0; mf < 2; ++mf)
                #pragma unroll
                for (int nf = 0; nf < 2; ++nf)
                    #pragma unroll
                    for (int r = 0; r < 4; ++r) {
                        int key = kt * 32 + nf * 16 + c;
                        int q   = qrow0 + mf * 16 + g * 4 + r;
                        if (key > q) s[mf][nf][r] = -INFINITY;
                    }
        }

        // ---- online softmax ----
        #pragma unroll
        for (int mf = 0; mf < 2; ++mf) {
            float tmax[4];
            #pragma unroll
            for (int r = 0; r < 4; ++r) tmax[r] = fmaxf(s[mf][0][r], s[mf][1][r]);
            #pragma unroll
            for (int d = 1; d < 16; d <<= 1)
                #pragma unroll
                for (int r = 0; r < 4; ++r) tmax[r] = fmaxf(tmax[r], __shfl_xor(tmax[r], d));
            float nm[4], corr[4];
            #pragma unroll
            for (int r = 0; r < 4; ++r) {
                nm[r]   = fmaxf(mrun[mf][r], tmax[r]);
                corr[r] = __expf(mrun[mf][r] - nm[r]);   // 0 when mrun=-inf
                mrun[mf][r] = nm[r];
            }
            float rs[4] = {0.f, 0.f, 0.f, 0.f};
            #pragma unroll
            for (int nf = 0; nf < 2; ++nf)
                #pragma unroll
                for (int r = 0; r < 4; ++r) {
                    float p  = __expf(s[mf][nf][r] - nm[r]);
                    ushort ph = f2bf(p);
                    Pl[w][(mf * 16 + g * 4 + r) * 48 + nf * 16 + c] = ph;
                    rs[r] += bf2f(ph);                   // sum of quantized P
                }
            #pragma unroll
            for (int d = 1; d < 16; d <<= 1)
                #pragma unroll
                for (int r = 0; r < 4; ++r) rs[r] += __shfl_xor(rs[r], d);
            #pragma unroll
            for (int r = 0; r < 4; ++r) lrun[mf][r] = lrun[mf][r] * corr[r] + rs[r];
            #pragma unroll
            for (int nf = 0; nf < 4; ++nf)
                #pragma unroll
                for (int r = 0; r < 4; ++r) o[mf][nf][r] *= corr[r];
        }

        // ---- O += P V  (P bf16 from LDS, V hi/lo) ----
        bf16x8 pa[2];
        #pragma unroll
        for (int mf = 0; mf < 2; ++mf)
            pa[mf] = *(const bf16x8*)&Pl[w][(mf * 16 + c) * 48 + g * 8];
        bf16x8 vhf[4], vlf[4];
        #pragma unroll
        for (int nf = 0; nf < 4; ++nf) {
            int d = nf * 16 + c;
            vhf[nf] = *(const bf16x8*)&Vhi[d * 48 + g * 8];
            vlf[nf] = *(const bf16x8*)&Vlo[d * 48 + g * 8];
        }
        #pragma unroll
        for (int mf = 0; mf < 2; ++mf)
            #pragma unroll
            for (int nf = 0; nf < 4; ++nf) {
                o[mf][nf] = __builtin_amdgcn_mfma_f32_16x16x32_bf16(pa[mf], vhf[nf], o[mf][nf], 0, 0, 0);
                o[mf][nf] = __builtin_amdgcn_mfma_f32_16x16x32_bf16(pa[mf], vlf[nf], o[mf][nf], 0, 0, 0);
            }
    }

    // ---- epilogue: O / L -> ctx [N,T,D] ----
    int n = nh / NH, h = nh % NH;
    #pragma unroll
    for (int mf = 0; mf < 2; ++mf) {
        float inv[4];
        #pragma unroll
        for (int r = 0; r < 4; ++r) inv[r] = 1.0f / lrun[mf][r];
        #pragma unroll
        for (int nf = 0; nf < 4; ++nf)
            #pragma unroll
            for (int r = 0; r < 4; ++r) {
                int q = qrow0 + mf * 16 + g * 4 + r;
                int d = nf * 16 + c;
                ctx[((size_t)(n * TS + q)) * DM + h * HD + d] = o[mf][nf][r] * inv[r];
            }
    }
}

// ---------------- out projection (fp32 VALU, unchanged) ----------------
__global__ __launch_bounds__(256) void outproj_gemm_k(
    const float* __restrict__ X, const float* __restrict__ W, float* __restrict__ out) {
    __shared__ float As[32 * 68];
    __shared__ float Bs[32 * 68];
    int tid  = threadIdx.x;
    int row0 = blockIdx.x * 64;
    int col0 = blockIdx.y * 64;
    int tr = (tid >> 4) << 2;
    int tc = (tid & 15) << 2;
    float acc[4][4] = {};

    for (int kt = 0; kt < DM; kt += 32) {
        __syncthreads();
        #pragma unroll
        for (int j = 0; j < 2; ++j) {
            int li = tid + j * 256;
            int m  = li >> 3;
            int k4 = (li & 7) << 2;
            float4 av = *(const float4*)&X[(size_t)(row0 + m) * DM + kt + k4];
            As[(k4+0)*68 + m] = av.x; As[(k4+1)*68 + m] = av.y;
            As[(k4+2)*68 + m] = av.z; As[(k4+3)*68 + m] = av.w;
            float4 bv = *(const float4*)&W[(size_t)(col0 + m) * DM + kt + k4];
            Bs[(k4+0)*68 + m] = bv.x; Bs[(k4+1)*68 + m] = bv.y;
            Bs[(k4+2)*68 + m] = bv.z; Bs[(k4+3)*68 + m] = bv.w;
        }
        __syncthreads();
        #pragma unroll
        for (int k = 0; k < 32; ++k) {
            float4 a = *(float4*)&As[k*68 + tr];
            float4 b = *(float4*)&Bs[k*68 + tc];
            acc[0][0] = fmaf(a.x, b.x, acc[0][0]); acc[0][1] = fmaf(a.x, b.y, acc[0][1]);
            acc[0][2] = fmaf(a.x, b.z, acc[0][2]); acc[0][3] = fmaf(a.x, b.w, acc[0][3]);
            acc[1][0] = fmaf(a.y, b.x, acc[1][0]); acc[1][1] = fmaf(a.y, b.y, acc[1][1]);
            acc[1][2] = fmaf(a.y, b.z, acc[1][2]); acc[1][3] = fmaf(a.y, b.w, acc[1][3]);
            acc[2][0] = fmaf(a.z, b.x, acc[2][0]); acc[2][1] = fmaf(a.z, b.y, acc[2][1]);
            acc[2][2] = fmaf(a.z, b.z, acc[2][2]); acc[2][3] = fmaf(a.z, b.w, acc[2][3]);
            acc[3][0] = fmaf(a.w, b.x, acc[3][0]); acc[3][1] = fmaf(a.w, b.y, acc[3][1]);
            acc[3][2] = fmaf(a.w, b.z, acc[3][2]); acc[3][3] = fmaf(a.w, b.w, acc[3][3]);
        }
    }
    #pragma unroll
    for (int i = 0; i < 4; ++i) {
        int r = row0 + tr + i;
        float4 ov = make_float4(acc[i][0], acc[i][1], acc[i][2], acc[i][3]);
        *(float4*)&out[(size_t)r * DM + col0 + tc] = ov;
    }
}

extern "C" void kernel_launch(void* const* d_in, const int* in_sizes, int n_in,
                              void* d_out, int out_size, void* d_ws, size_t ws_size,
                              hipStream_t stream) {
    const float* x    = (const float*)d_in[0];
    const float* Wqkv = (const float*)d_in[1];
    const float* Wout = (const float*)d_in[2];
    float* out = (float*)d_out;

    float* ws   = (float*)d_ws;
    const size_t NHT = (size_t)NB * NH * TS * HD;
    float* cosT = ws;
    float* sinT = cosT + TS * HD;
    float* qb   = sinT + TS * HD;
    float* kb   = qb + NHT;
    float* vb   = kb + NHT;
    float* ctx  = vb + NHT;

    rope_table_k<<<(TS * HD) / 256, 256, 0, stream>>>(cosT, sinT);
    qkv_gemm_k<<<dim3(MROWS / 64, E3 / 64), 256, 0, stream>>>(x, Wqkv, qb, kb, vb);
    rope_apply_k<<<(2 * NB * NH * TS * 32) / 256, 256, 0, stream>>>(qb, kb, cosT, sinT);
    flash_mfma_k<<<dim3(TS / 128, NB * NH), 256, 0, stream>>>(qb, kb, vb, ctx);
    outproj_gemm_k<<<dim3(MROWS / 64, DM / 64), 256, 0, stream>>>(ctx, Wout, out);
}